// Round 16
// baseline (124.292 us; speedup 1.0000x reference)
//
#include <hip/hip_runtime.h>

#define B_  2
#define V_  4
#define VS_ 3   // source views
#define C_  32
#define G_  8
#define D_  32
#define H_  128
#define W_  160
#define CELLS_MAX 128   // nx<=16 * ny<=8

// ---------------------------------------------------------------------------
// 4x4 inverse (Gauss-Jordan with partial pivoting)
// ---------------------------------------------------------------------------
__device__ void inv4x4(const float* m, float* out) {
    float a[4][8];
    for (int i = 0; i < 4; i++) {
        for (int j = 0; j < 4; j++) {
            a[i][j]     = m[i * 4 + j];
            a[i][j + 4] = (i == j) ? 1.f : 0.f;
        }
    }
    for (int c = 0; c < 4; c++) {
        int piv = c;
        float best = fabsf(a[c][c]);
        for (int r = c + 1; r < 4; r++) {
            float v = fabsf(a[r][c]);
            if (v > best) { best = v; piv = r; }
        }
        if (piv != c) {
            for (int j = 0; j < 8; j++) {
                float t = a[c][j]; a[c][j] = a[piv][j]; a[piv][j] = t;
            }
        }
        float pv = 1.f / a[c][c];
        for (int j = 0; j < 8; j++) a[c][j] *= pv;
        for (int r = 0; r < 4; r++) {
            if (r == c) continue;
            float f = a[r][c];
            for (int j = 0; j < 8; j++) a[r][j] -= f * a[c][j];
        }
    }
    for (int i = 0; i < 4; i++)
        for (int j = 0; j < 4; j++) out[i * 4 + j] = a[i][j + 4];
}

__device__ void make_proj(const float* p, float* o) {
    const float* ext = p;
    const float* K   = p + 16;
    for (int i = 0; i < 16; i++) o[i] = ext[i];
    for (int i = 0; i < 3; i++) {
        for (int j = 0; j < 4; j++) {
            float s = 0.f;
            for (int k = 0; k < 3; k++) s += K[i * 4 + k] * ext[k * 4 + j];
            o[i * 4 + j] = s;
        }
    }
}

// Per (b, src view): store rot(9) + trans(3) of src_proj @ inv(ref_proj)
__global__ void setup_proj_kernel(const float* __restrict__ proj,
                                  float* __restrict__ projp) {
    int t = threadIdx.x;
    if (t >= B_ * VS_) return;
    int b = t / VS_;
    int v = t % VS_ + 1;

    float refm[16], srcm[16], invr[16], P[16];
    make_proj(proj + ((size_t)(b * V_ + 0) * 2) * 16, refm);
    make_proj(proj + ((size_t)(b * V_ + v) * 2) * 16, srcm);
    inv4x4(refm, invr);
    for (int i = 0; i < 4; i++) {
        for (int j = 0; j < 4; j++) {
            float s = 0.f;
            for (int k = 0; k < 4; k++) s += srcm[i * 4 + k] * invr[k * 4 + j];
            P[i * 4 + j] = s;
        }
    }
    float* o = projp + t * 12;
    o[0] = P[0];  o[1] = P[1];  o[2]  = P[2];
    o[3] = P[4];  o[4] = P[5];  o[5]  = P[6];
    o[6] = P[8];  o[7] = P[9];  o[8]  = P[10];
    o[9] = P[3];  o[10] = P[7]; o[11] = P[11];
}

// ---------------------------------------------------------------------------
// (N, C, H, W) -> (N, H, W, C) fp32 channels-last transpose
// ---------------------------------------------------------------------------
__global__ __launch_bounds__(256) void transpose_kernel(const float* __restrict__ in,
                                                        float* __restrict__ out) {
    __shared__ float tile[C_][W_ + 1];
    int n = blockIdx.x / H_;
    int y = blockIdx.x % H_;
    for (int idx = threadIdx.x; idx < C_ * W_; idx += 256) {
        int c = idx / W_;
        int x = idx - c * W_;
        tile[c][x] = in[(((size_t)n * C_ + c) * H_ + y) * W_ + x];
    }
    __syncthreads();
    float* op = out + ((size_t)n * H_ + y) * W_ * C_;
    for (int idx = threadIdx.x; idx < W_ * C_; idx += 256) {
        int c = idx & (C_ - 1);
        int x = idx >> 5;
        op[idx] = tile[c][x];
    }
}

// ---------------------------------------------------------------------------
// Fused kernel: r15 passing structure with ONE change — exact-nc row-major
// cell mapping (no pow2 pitch, no masked lanes) via the (ci+0.5)*(1/nx)
// float-division trick (exact for ci<128, nx<=16).
// Block = 8 pixels x 32 depths.
// ---------------------------------------------------------------------------
__global__ __launch_bounds__(256) void fused_kernel(const float* __restrict__ ref_fea,
                                                    const float* __restrict__ srcT,
                                                    const float* __restrict__ projp,
                                                    const float* __restrict__ depth_hypo,
                                                    const float* __restrict__ reg_w,
                                                    float* __restrict__ out) {
    const int WT = W_ / 8;
    int bid = blockIdx.x;
    int b   = bid / (H_ * WT);
    int rem = bid % (H_ * WT);
    int h   = rem / WT;
    int w0  = (rem % WT) * 8;

    int tid = threadIdx.x;
    int d   = tid & 31;
    int p   = tid >> 5;
    int w   = w0 + p;

    __shared__ float  s_ref[8][36];
    __shared__ float  s_depth[8][33];
    __shared__ float2 s_dot[2][8][CELLS_MAX];   // 16 KB, double-buffered
    {
        int c  = tid >> 3;
        int px = tid & 7;
        s_ref[px][c]   = ref_fea[(((size_t)b * C_ + c) * H_ + h) * W_ + w0 + px];
        s_depth[px][c] = depth_hypo[(((size_t)b * D_ + c) * H_ + h) * W_ + w0 + px];
    }

    // reg_w is wave-uniform -> scalar regs (plain loads)
    float rwv[G_];
#pragma unroll
    for (int g = 0; g < G_; ++g) rwv[g] = reg_w[g];

    __syncthreads();

    float depth = s_depth[p][d];
    float d_lo  = s_depth[p][0];
    float d_hi  = s_depth[p][31];
    float xf = (float)w, yf = (float)h;

    // bbox state for current view (uniform across the 32 lanes of a pixel)
    int xmn, ymn, nx, ny;

    // phase 1: compute per-cell dots for view v into s_dot[v&1]
    auto phase1 = [&](int v) {
        const float* M = projp + (b * VS_ + v) * 12;
        float rx = M[0] * xf + M[1] * yf + M[2];
        float ry = M[3] * xf + M[4] * yf + M[5];
        float rz = M[6] * xf + M[7] * yf + M[8];

        float Zl = rz * d_lo + M[11]; if (Zl == 0.f) Zl = 1e-9f;
        float Zh = rz * d_hi + M[11]; if (Zh == 0.f) Zh = 1e-9f;
        float il = 1.f / Zl, ih = 1.f / Zh;
        float xl = (rx * d_lo + M[9]) * il, yl = (ry * d_lo + M[10]) * il;
        float xh = (rx * d_hi + M[9]) * ih, yh = (ry * d_hi + M[10]) * ih;

        float xmnf = fminf(fmaxf(fminf(xl, xh), -2.f), (float)(W_ + 1));
        float xmxf = fminf(fmaxf(fmaxf(xl, xh), -2.f), (float)(W_ + 1));
        float ymnf = fminf(fmaxf(fminf(yl, yh), -2.f), (float)(H_ + 1));
        float ymxf = fminf(fmaxf(fmaxf(yl, yh), -2.f), (float)(H_ + 1));

        xmn = max((int)floorf(xmnf), -1);
        ymn = max((int)floorf(ymnf), -1);
        int xmx = min(max((int)floorf(xmxf), xmn), min(W_ - 1, xmn + 14));
        int ymx = min(max((int)floorf(ymxf), ymn), min(H_ - 1, ymn + 6));
        nx = xmx - xmn + 2;                 // cells cover [xmn .. xmx+1]
        ny = ymx - ymn + 2;
        int nc = nx * ny;                   // <= 128, exact (no pitch padding)
        float uinv = 1.f / (float)nx;

        const float4* sp = (const float4*)(srcT + (size_t)(v * B_ + b) * H_ * W_ * C_);
        float2* dot = &s_dot[v & 1][p][0];
        for (int ci = d; ci < nc; ci += 32) {
            int cy = (int)(((float)ci + 0.5f) * uinv);   // exact floor(ci/nx)
            int cx = ci - cy * nx;
            int sx = min(max(xmn + cx, 0), W_ - 1);
            int sy = min(max(ymn + cy, 0), H_ - 1);
            const float4* cp = sp + ((size_t)sy * W_ + sx) * (C_ / 4);
            float dS = 0.f, dR = 0.f;
#pragma unroll
            for (int q = 0; q < 8; ++q) {
                float4 sv = cp[q];
                float4 r  = *(const float4*)&s_ref[p][q * 4];
                float gq = r.x * sv.x + r.y * sv.y + r.z * sv.z + r.w * sv.w;
                dS += gq;
                dR += rwv[q] * gq;
            }
            dot[ci] = make_float2(dS, dR);
        }
    };

    float cwsum = 1e-8f;
    float acc   = 0.f;

    phase1(0);
    __syncthreads();

    for (int v = 0; v < VS_; ++v) {
        // save current view's bbox (phase1(v+1) overwrites the uniforms)
        int cxmn = xmn, cymn = ymn, cnx = nx, cny = ny;

        if (v + 1 < VS_) phase1(v + 1);   // loads overlap phase-2 compute below

        // ---- phase 2: per-depth bilinear combine + view softmax ----
        const float* M = projp + (b * VS_ + v) * 12;
        float rx = M[0] * xf + M[1] * yf + M[2];
        float ry = M[3] * xf + M[4] * yf + M[5];
        float rz = M[6] * xf + M[7] * yf + M[8];
        float Z = rz * depth + M[11]; if (Z == 0.f) Z = 1e-9f;
        float iZ = 1.f / Z;
        float ix = (rx * depth + M[9]) * iZ;
        float iy = (ry * depth + M[10]) * iZ;
        float x0f = floorf(ix), y0f = floorf(iy);
        float wx1 = ix - x0f, wy1 = iy - y0f;
        float wx0 = 1.f - wx1, wy0 = 1.f - wy1;

        int x0 = (int)fminf(fmaxf(x0f, -2.f), (float)(W_ + 1));
        int y0 = (int)fminf(fmaxf(y0f, -2.f), (float)(H_ + 1));

        float vx0 = (x0f >= 0.f  && x0f <= (float)(W_ - 1)) ? 1.f : 0.f;
        float vx1 = (x0f >= -1.f && x0f <= (float)(W_ - 2)) ? 1.f : 0.f;
        float vy0 = (y0f >= 0.f  && y0f <= (float)(H_ - 1)) ? 1.f : 0.f;
        float vy1 = (y0f >= -1.f && y0f <= (float)(H_ - 2)) ? 1.f : 0.f;
        float ax0 = wx0 * vx0, ax1 = wx1 * vx1;
        float ay0 = wy0 * vy0, ay1 = wy1 * vy1;
        float w00 = ax0 * ay0, w10 = ax1 * ay0;
        float w01 = ax0 * ay1, w11 = ax1 * ay1;

        int cx0 = min(max(x0 - cxmn, 0), cnx - 2);
        int cy0 = min(max(y0 - cymn, 0), cny - 2);
        const float2* dot = &s_dot[v & 1][p][0];
        int cb = cy0 * cnx + cx0;
        float2 d00 = dot[cb],       d10 = dot[cb + 1];
        float2 d01 = dot[cb + cnx], d11 = dot[cb + cnx + 1];
        float S = w00 * d00.x + w10 * d10.x + w01 * d01.x + w11 * d11.x;
        float R = w00 * d00.y + w10 * d10.y + w01 * d01.y + w11 * d11.y;

        // view softmax over D (32-lane butterfly)
        float t = S * 0.125f;   // *0.25 (group mean) * 0.5 (1/ATTN_TEMP)
        float m = t;
#pragma unroll
        for (int mask = 16; mask >= 1; mask >>= 1)
            m = fmaxf(m, __shfl_xor(m, mask));
        float e = __expf(t - m);
        float s = e;
#pragma unroll
        for (int mask = 16; mask >= 1; mask >>= 1)
            s += __shfl_xor(s, mask);
        float cw = e / s * 0.17677669529663689f;   // * 1/sqrt(C)
        cwsum += cw;
        acc   += cw * (R * 0.25f);

        __syncthreads();   // phase1(v+1) writes done; dot[v&1] free for v+2
    }

    float logit = acc / cwsum;

    // final softmax over D
    float m = logit;
#pragma unroll
    for (int mask = 16; mask >= 1; mask >>= 1)
        m = fmaxf(m, __shfl_xor(m, mask));
    float e = __expf(logit - m);
    float s = e;
#pragma unroll
    for (int mask = 16; mask >= 1; mask >>= 1)
        s += __shfl_xor(s, mask);
    float attn = e / s;

    // argmax over D (first max wins, matching jnp.argmax)
    float bv = logit;
    int   bi = d;
#pragma unroll
    for (int mask = 16; mask >= 1; mask >>= 1) {
        float ov = __shfl_xor(bv, mask);
        int   oi = __shfl_xor(bi, mask);
        if (ov > bv || (ov == bv && oi < bi)) { bv = ov; bi = oi; }
    }

    if (d == 0) {
        out[((size_t)b * H_ + h) * W_ + w] = s_depth[p][bi];
    }

    // attn store via LDS transpose for 32B-segment coalescing
    __shared__ float s_attn[8][33];
    s_attn[p][d] = attn;
    __syncthreads();
    int po = tid & 7;
    int d2 = tid >> 3;
    float* attn_out = out + (size_t)B_ * H_ * W_;
    attn_out[(((size_t)b * D_ + d2) * H_ + h) * W_ + w0 + po] = s_attn[po][d2];
}

// ---------------------------------------------------------------------------
extern "C" void kernel_launch(void* const* d_in, const int* in_sizes, int n_in,
                              void* d_out, int out_size, void* d_ws, size_t ws_size,
                              hipStream_t stream) {
    const float* ref_fea    = (const float*)d_in[0];
    const float* src_feas   = (const float*)d_in[1];
    const float* proj       = (const float*)d_in[2];
    const float* depth_hypo = (const float*)d_in[3];
    const float* reg_w      = (const float*)d_in[4];
    float* out = (float*)d_out;

    float* projp = (float*)d_ws;                       // 72 floats used
    float* srcT  = projp + 256;                        // VS*B*H*W*C fp32

    setup_proj_kernel<<<1, 64, 0, stream>>>(proj, projp);
    transpose_kernel<<<VS_ * B_ * H_, 256, 0, stream>>>(src_feas, srcT);
    fused_kernel<<<B_ * H_ * (W_ / 8), 256, 0, stream>>>(ref_fea, srcT, projp,
                                                         depth_hypo, reg_w, out);
}

// Round 17
// 89.240 us; speedup vs baseline: 1.3928x; 1.3928x over previous
//
#include <hip/hip_runtime.h>

#define B_  2
#define V_  4
#define VS_ 3   // source views
#define C_  32
#define G_  8
#define D_  32
#define H_  128
#define W_  160
#define CELLS_MAX 128   // nx<=16 (pitch) * ny<=8

// ---------------------------------------------------------------------------
// 4x4 inverse (Gauss-Jordan with partial pivoting)
// ---------------------------------------------------------------------------
__device__ void inv4x4(const float* m, float* out) {
    float a[4][8];
    for (int i = 0; i < 4; i++) {
        for (int j = 0; j < 4; j++) {
            a[i][j]     = m[i * 4 + j];
            a[i][j + 4] = (i == j) ? 1.f : 0.f;
        }
    }
    for (int c = 0; c < 4; c++) {
        int piv = c;
        float best = fabsf(a[c][c]);
        for (int r = c + 1; r < 4; r++) {
            float v = fabsf(a[r][c]);
            if (v > best) { best = v; piv = r; }
        }
        if (piv != c) {
            for (int j = 0; j < 8; j++) {
                float t = a[c][j]; a[c][j] = a[piv][j]; a[piv][j] = t;
            }
        }
        float pv = 1.f / a[c][c];
        for (int j = 0; j < 8; j++) a[c][j] *= pv;
        for (int r = 0; r < 4; r++) {
            if (r == c) continue;
            float f = a[r][c];
            for (int j = 0; j < 8; j++) a[r][j] -= f * a[c][j];
        }
    }
    for (int i = 0; i < 4; i++)
        for (int j = 0; j < 4; j++) out[i * 4 + j] = a[i][j + 4];
}

__device__ void make_proj(const float* p, float* o) {
    const float* ext = p;
    const float* K   = p + 16;
    for (int i = 0; i < 16; i++) o[i] = ext[i];
    for (int i = 0; i < 3; i++) {
        for (int j = 0; j < 4; j++) {
            float s = 0.f;
            for (int k = 0; k < 3; k++) s += K[i * 4 + k] * ext[k * 4 + j];
            o[i * 4 + j] = s;
        }
    }
}

// Per (b, src view): store rot(9) + trans(3) of src_proj @ inv(ref_proj)
__global__ void setup_proj_kernel(const float* __restrict__ proj,
                                  float* __restrict__ projp) {
    int t = threadIdx.x;
    if (t >= B_ * VS_) return;
    int b = t / VS_;
    int v = t % VS_ + 1;

    float refm[16], srcm[16], invr[16], P[16];
    make_proj(proj + ((size_t)(b * V_ + 0) * 2) * 16, refm);
    make_proj(proj + ((size_t)(b * V_ + v) * 2) * 16, srcm);
    inv4x4(refm, invr);
    for (int i = 0; i < 4; i++) {
        for (int j = 0; j < 4; j++) {
            float s = 0.f;
            for (int k = 0; k < 4; k++) s += srcm[i * 4 + k] * invr[k * 4 + j];
            P[i * 4 + j] = s;
        }
    }
    float* o = projp + t * 12;
    o[0] = P[0];  o[1] = P[1];  o[2]  = P[2];
    o[3] = P[4];  o[4] = P[5];  o[5]  = P[6];
    o[6] = P[8];  o[7] = P[9];  o[8]  = P[10];
    o[9] = P[3];  o[10] = P[7]; o[11] = P[11];
}

// ---------------------------------------------------------------------------
// (N, C, H, W) -> (N, H, W, C) fp32 channels-last transpose
// ---------------------------------------------------------------------------
__global__ __launch_bounds__(256) void transpose_kernel(const float* __restrict__ in,
                                                        float* __restrict__ out) {
    __shared__ float tile[C_][W_ + 1];
    int n = blockIdx.x / H_;
    int y = blockIdx.x % H_;
    for (int idx = threadIdx.x; idx < C_ * W_; idx += 256) {
        int c = idx / W_;
        int x = idx - c * W_;
        tile[c][x] = in[(((size_t)n * C_ + c) * H_ + y) * W_ + x];
    }
    __syncthreads();
    float* op = out + ((size_t)n * H_ + y) * W_ * C_;
    for (int idx = threadIdx.x; idx < W_ * C_; idx += 256) {
        int c = idx & (C_ - 1);
        int x = idx >> 5;
        op[idx] = tile[c][x];
    }
}

// ---------------------------------------------------------------------------
// Fused kernel: the round-15 passing artifact, byte-for-byte (group-dot
// factorization, pow2-pitch cell mapping, compiler-chosen registers).
// r16's exact-nc mapping regressed VGPR 40->112 (runtime-stride loop defeated
// the allocator); the pow2 indexing is what keeps this in the 40-VGPR bin.
// Block = 8 pixels x 32 depths.
// ---------------------------------------------------------------------------
__global__ __launch_bounds__(256) void fused_kernel(const float* __restrict__ ref_fea,
                                                    const float* __restrict__ srcT,
                                                    const float* __restrict__ projp,
                                                    const float* __restrict__ depth_hypo,
                                                    const float* __restrict__ reg_w,
                                                    float* __restrict__ out) {
    const int WT = W_ / 8;
    int bid = blockIdx.x;
    int b   = bid / (H_ * WT);
    int rem = bid % (H_ * WT);
    int h   = rem / WT;
    int w0  = (rem % WT) * 8;

    int tid = threadIdx.x;
    int d   = tid & 31;
    int p   = tid >> 5;
    int w   = w0 + p;

    __shared__ float  s_ref[8][36];
    __shared__ float  s_depth[8][33];
    __shared__ float2 s_dot[2][8][CELLS_MAX];   // 16 KB, double-buffered
    {
        int c  = tid >> 3;
        int px = tid & 7;
        s_ref[px][c]   = ref_fea[(((size_t)b * C_ + c) * H_ + h) * W_ + w0 + px];
        s_depth[px][c] = depth_hypo[(((size_t)b * D_ + c) * H_ + h) * W_ + w0 + px];
    }

    // reg_w is wave-uniform -> scalar regs (plain loads)
    float rwv[G_];
#pragma unroll
    for (int g = 0; g < G_; ++g) rwv[g] = reg_w[g];

    __syncthreads();

    float depth = s_depth[p][d];
    float d_lo  = s_depth[p][0];
    float d_hi  = s_depth[p][31];
    float xf = (float)w, yf = (float)h;

    // bbox state for current view (uniform across the 32 lanes of a pixel)
    int xmn, ymn, nx, ny, nxp, shp;

    // phase 1: compute per-cell dots for view v into s_dot[v&1]
    auto phase1 = [&](int v) {
        const float* M = projp + (b * VS_ + v) * 12;
        float rx = M[0] * xf + M[1] * yf + M[2];
        float ry = M[3] * xf + M[4] * yf + M[5];
        float rz = M[6] * xf + M[7] * yf + M[8];

        float Zl = rz * d_lo + M[11]; if (Zl == 0.f) Zl = 1e-9f;
        float Zh = rz * d_hi + M[11]; if (Zh == 0.f) Zh = 1e-9f;
        float il = 1.f / Zl, ih = 1.f / Zh;
        float xl = (rx * d_lo + M[9]) * il, yl = (ry * d_lo + M[10]) * il;
        float xh = (rx * d_hi + M[9]) * ih, yh = (ry * d_hi + M[10]) * ih;

        float xmnf = fminf(fmaxf(fminf(xl, xh), -2.f), (float)(W_ + 1));
        float xmxf = fminf(fmaxf(fmaxf(xl, xh), -2.f), (float)(W_ + 1));
        float ymnf = fminf(fmaxf(fminf(yl, yh), -2.f), (float)(H_ + 1));
        float ymxf = fminf(fmaxf(fmaxf(yl, yh), -2.f), (float)(H_ + 1));

        xmn = max((int)floorf(xmnf), -1);
        ymn = max((int)floorf(ymnf), -1);
        int xmx = min(max((int)floorf(xmxf), xmn), min(W_ - 1, xmn + 14));
        int ymx = min(max((int)floorf(ymxf), ymn), min(H_ - 1, ymn + 6));
        nx = xmx - xmn + 2;                 // cells cover [xmn .. xmx+1]
        ny = ymx - ymn + 2;
        shp = (nx <= 4) ? 2 : ((nx <= 8) ? 3 : 4);
        nxp = 1 << shp;
        int ncp = nxp * ny;                 // <= 128

        const float4* sp = (const float4*)(srcT + (size_t)(v * B_ + b) * H_ * W_ * C_);
        float2* dot = &s_dot[v & 1][p][0];
        for (int ci = d; ci < ncp; ci += 32) {
            int cx = ci & (nxp - 1);
            if (cx < nx) {
                int cy = ci >> shp;
                int sx = min(max(xmn + cx, 0), W_ - 1);
                int sy = min(max(ymn + cy, 0), H_ - 1);
                const float4* cp = sp + ((size_t)sy * W_ + sx) * (C_ / 4);
                float dS = 0.f, dR = 0.f;
#pragma unroll
                for (int q = 0; q < 8; ++q) {
                    float4 sv = cp[q];
                    float4 r  = *(const float4*)&s_ref[p][q * 4];
                    float gq = r.x * sv.x + r.y * sv.y + r.z * sv.z + r.w * sv.w;
                    dS += gq;
                    dR += rwv[q] * gq;
                }
                dot[ci] = make_float2(dS, dR);
            }
        }
    };

    float cwsum = 1e-8f;
    float acc   = 0.f;

    phase1(0);
    __syncthreads();

    for (int v = 0; v < VS_; ++v) {
        // save current view's bbox (phase1(v+1) overwrites the uniforms)
        int cxmn = xmn, cymn = ymn, cnx = nx, cny = ny, cnxp = nxp;

        if (v + 1 < VS_) phase1(v + 1);   // loads overlap phase-2 compute below

        // ---- phase 2: per-depth bilinear combine + view softmax ----
        const float* M = projp + (b * VS_ + v) * 12;
        float rx = M[0] * xf + M[1] * yf + M[2];
        float ry = M[3] * xf + M[4] * yf + M[5];
        float rz = M[6] * xf + M[7] * yf + M[8];
        float Z = rz * depth + M[11]; if (Z == 0.f) Z = 1e-9f;
        float iZ = 1.f / Z;
        float ix = (rx * depth + M[9]) * iZ;
        float iy = (ry * depth + M[10]) * iZ;
        float x0f = floorf(ix), y0f = floorf(iy);
        float wx1 = ix - x0f, wy1 = iy - y0f;
        float wx0 = 1.f - wx1, wy0 = 1.f - wy1;

        int x0 = (int)fminf(fmaxf(x0f, -2.f), (float)(W_ + 1));
        int y0 = (int)fminf(fmaxf(y0f, -2.f), (float)(H_ + 1));

        float vx0 = (x0f >= 0.f  && x0f <= (float)(W_ - 1)) ? 1.f : 0.f;
        float vx1 = (x0f >= -1.f && x0f <= (float)(W_ - 2)) ? 1.f : 0.f;
        float vy0 = (y0f >= 0.f  && y0f <= (float)(H_ - 1)) ? 1.f : 0.f;
        float vy1 = (y0f >= -1.f && y0f <= (float)(H_ - 2)) ? 1.f : 0.f;
        float ax0 = wx0 * vx0, ax1 = wx1 * vx1;
        float ay0 = wy0 * vy0, ay1 = wy1 * vy1;
        float w00 = ax0 * ay0, w10 = ax1 * ay0;
        float w01 = ax0 * ay1, w11 = ax1 * ay1;

        int cx0 = min(max(x0 - cxmn, 0), cnx - 2);
        int cy0 = min(max(y0 - cymn, 0), cny - 2);
        const float2* dot = &s_dot[v & 1][p][0];
        int cb = cy0 * cnxp + cx0;
        float2 d00 = dot[cb],        d10 = dot[cb + 1];
        float2 d01 = dot[cb + cnxp], d11 = dot[cb + cnxp + 1];
        float S = w00 * d00.x + w10 * d10.x + w01 * d01.x + w11 * d11.x;
        float R = w00 * d00.y + w10 * d10.y + w01 * d01.y + w11 * d11.y;

        // view softmax over D (32-lane butterfly)
        float t = S * 0.125f;   // *0.25 (group mean) * 0.5 (1/ATTN_TEMP)
        float m = t;
#pragma unroll
        for (int mask = 16; mask >= 1; mask >>= 1)
            m = fmaxf(m, __shfl_xor(m, mask));
        float e = __expf(t - m);
        float s = e;
#pragma unroll
        for (int mask = 16; mask >= 1; mask >>= 1)
            s += __shfl_xor(s, mask);
        float cw = e / s * 0.17677669529663689f;   // * 1/sqrt(C)
        cwsum += cw;
        acc   += cw * (R * 0.25f);

        __syncthreads();   // phase1(v+1) writes done; dot[v&1] free for v+2
    }

    float logit = acc / cwsum;

    // final softmax over D
    float m = logit;
#pragma unroll
    for (int mask = 16; mask >= 1; mask >>= 1)
        m = fmaxf(m, __shfl_xor(m, mask));
    float e = __expf(logit - m);
    float s = e;
#pragma unroll
    for (int mask = 16; mask >= 1; mask >>= 1)
        s += __shfl_xor(s, mask);
    float attn = e / s;

    // argmax over D (first max wins, matching jnp.argmax)
    float bv = logit;
    int   bi = d;
#pragma unroll
    for (int mask = 16; mask >= 1; mask >>= 1) {
        float ov = __shfl_xor(bv, mask);
        int   oi = __shfl_xor(bi, mask);
        if (ov > bv || (ov == bv && oi < bi)) { bv = ov; bi = oi; }
    }

    if (d == 0) {
        out[((size_t)b * H_ + h) * W_ + w] = s_depth[p][bi];
    }

    // attn store via LDS transpose for 32B-segment coalescing
    __shared__ float s_attn[8][33];
    s_attn[p][d] = attn;
    __syncthreads();
    int po = tid & 7;
    int d2 = tid >> 3;
    float* attn_out = out + (size_t)B_ * H_ * W_;
    attn_out[(((size_t)b * D_ + d2) * H_ + h) * W_ + w0 + po] = s_attn[po][d2];
}

// ---------------------------------------------------------------------------
extern "C" void kernel_launch(void* const* d_in, const int* in_sizes, int n_in,
                              void* d_out, int out_size, void* d_ws, size_t ws_size,
                              hipStream_t stream) {
    const float* ref_fea    = (const float*)d_in[0];
    const float* src_feas   = (const float*)d_in[1];
    const float* proj       = (const float*)d_in[2];
    const float* depth_hypo = (const float*)d_in[3];
    const float* reg_w      = (const float*)d_in[4];
    float* out = (float*)d_out;

    float* projp = (float*)d_ws;                       // 72 floats used
    float* srcT  = projp + 256;                        // VS*B*H*W*C fp32

    setup_proj_kernel<<<1, 64, 0, stream>>>(proj, projp);
    transpose_kernel<<<VS_ * B_ * H_, 256, 0, stream>>>(src_feas, srcT);
    fused_kernel<<<B_ * H_ * (W_ / 8), 256, 0, stream>>>(ref_fea, srcT, projp,
                                                         depth_hypo, reg_w, out);
}

// Round 18
// 88.296 us; speedup vs baseline: 1.4077x; 1.0107x over previous
//
#include <hip/hip_runtime.h>

#define B_  2
#define V_  4
#define VS_ 3   // source views
#define C_  32
#define G_  8
#define D_  32
#define H_  128
#define W_  160
#define CELLS_MAX 128   // nx<=16 (pitch) * ny<=8

// ---------------------------------------------------------------------------
// 4x4 inverse (Gauss-Jordan with partial pivoting)
// ---------------------------------------------------------------------------
__device__ void inv4x4(const float* m, float* out) {
    float a[4][8];
    for (int i = 0; i < 4; i++) {
        for (int j = 0; j < 4; j++) {
            a[i][j]     = m[i * 4 + j];
            a[i][j + 4] = (i == j) ? 1.f : 0.f;
        }
    }
    for (int c = 0; c < 4; c++) {
        int piv = c;
        float best = fabsf(a[c][c]);
        for (int r = c + 1; r < 4; r++) {
            float v = fabsf(a[r][c]);
            if (v > best) { best = v; piv = r; }
        }
        if (piv != c) {
            for (int j = 0; j < 8; j++) {
                float t = a[c][j]; a[c][j] = a[piv][j]; a[piv][j] = t;
            }
        }
        float pv = 1.f / a[c][c];
        for (int j = 0; j < 8; j++) a[c][j] *= pv;
        for (int r = 0; r < 4; r++) {
            if (r == c) continue;
            float f = a[r][c];
            for (int j = 0; j < 8; j++) a[r][j] -= f * a[c][j];
        }
    }
    for (int i = 0; i < 4; i++)
        for (int j = 0; j < 4; j++) out[i * 4 + j] = a[i][j + 4];
}

__device__ void make_proj(const float* p, float* o) {
    const float* ext = p;
    const float* K   = p + 16;
    for (int i = 0; i < 16; i++) o[i] = ext[i];
    for (int i = 0; i < 3; i++) {
        for (int j = 0; j < 4; j++) {
            float s = 0.f;
            for (int k = 0; k < 3; k++) s += K[i * 4 + k] * ext[k * 4 + j];
            o[i * 4 + j] = s;
        }
    }
}

// Per (b, src view): store rot(9) + trans(3) of src_proj @ inv(ref_proj)
__global__ void setup_proj_kernel(const float* __restrict__ proj,
                                  float* __restrict__ projp) {
    int t = threadIdx.x;
    if (t >= B_ * VS_) return;
    int b = t / VS_;
    int v = t % VS_ + 1;

    float refm[16], srcm[16], invr[16], P[16];
    make_proj(proj + ((size_t)(b * V_ + 0) * 2) * 16, refm);
    make_proj(proj + ((size_t)(b * V_ + v) * 2) * 16, srcm);
    inv4x4(refm, invr);
    for (int i = 0; i < 4; i++) {
        for (int j = 0; j < 4; j++) {
            float s = 0.f;
            for (int k = 0; k < 4; k++) s += srcm[i * 4 + k] * invr[k * 4 + j];
            P[i * 4 + j] = s;
        }
    }
    float* o = projp + t * 12;
    o[0] = P[0];  o[1] = P[1];  o[2]  = P[2];
    o[3] = P[4];  o[4] = P[5];  o[5]  = P[6];
    o[6] = P[8];  o[7] = P[9];  o[8]  = P[10];
    o[9] = P[3];  o[10] = P[7]; o[11] = P[11];
}

// ---------------------------------------------------------------------------
// (N, C, H, W) -> (N, H, W, C) fp32 channels-last transpose
// ---------------------------------------------------------------------------
__global__ __launch_bounds__(256) void transpose_kernel(const float* __restrict__ in,
                                                        float* __restrict__ out) {
    __shared__ float tile[C_][W_ + 1];
    int n = blockIdx.x / H_;
    int y = blockIdx.x % H_;
    for (int idx = threadIdx.x; idx < C_ * W_; idx += 256) {
        int c = idx / W_;
        int x = idx - c * W_;
        tile[c][x] = in[(((size_t)n * C_ + c) * H_ + y) * W_ + x];
    }
    __syncthreads();
    float* op = out + ((size_t)n * H_ + y) * W_ * C_;
    for (int idx = threadIdx.x; idx < W_ * C_; idx += 256) {
        int c = idx & (C_ - 1);
        int x = idx >> 5;
        op[idx] = tile[c][x];
    }
}

// ---------------------------------------------------------------------------
// Fused kernel: r15/r17 passing structure with ONE change — the 4 per-view
// __syncthreads() are REMOVED. s_dot data flow is provably intra-wave
// (pixel p <-> half-wave p bijection; both halves of a wave64 share one
// instruction stream), so the compiler's lgkmcnt tracking orders it; the
// barriers only forced vmcnt(0) drains that killed cross-view load overlap.
// Initial staging barrier and final s_attn barrier (cross-wave) are kept.
// Block = 8 pixels x 32 depths.
// ---------------------------------------------------------------------------
__global__ __launch_bounds__(256) void fused_kernel(const float* __restrict__ ref_fea,
                                                    const float* __restrict__ srcT,
                                                    const float* __restrict__ projp,
                                                    const float* __restrict__ depth_hypo,
                                                    const float* __restrict__ reg_w,
                                                    float* __restrict__ out) {
    const int WT = W_ / 8;
    int bid = blockIdx.x;
    int b   = bid / (H_ * WT);
    int rem = bid % (H_ * WT);
    int h   = rem / WT;
    int w0  = (rem % WT) * 8;

    int tid = threadIdx.x;
    int d   = tid & 31;
    int p   = tid >> 5;
    int w   = w0 + p;

    __shared__ float  s_ref[8][36];
    __shared__ float  s_depth[8][33];
    __shared__ float2 s_dot[2][8][CELLS_MAX];   // 16 KB, double-buffered
    {
        int c  = tid >> 3;
        int px = tid & 7;
        s_ref[px][c]   = ref_fea[(((size_t)b * C_ + c) * H_ + h) * W_ + w0 + px];
        s_depth[px][c] = depth_hypo[(((size_t)b * D_ + c) * H_ + h) * W_ + w0 + px];
    }

    // reg_w is wave-uniform -> scalar regs (plain loads)
    float rwv[G_];
#pragma unroll
    for (int g = 0; g < G_; ++g) rwv[g] = reg_w[g];

    __syncthreads();   // cross-wave staging of s_ref/s_depth: barrier REQUIRED

    float depth = s_depth[p][d];
    float d_lo  = s_depth[p][0];
    float d_hi  = s_depth[p][31];
    float xf = (float)w, yf = (float)h;

    // bbox state for current view (uniform across the 32 lanes of a pixel)
    int xmn, ymn, nx, ny, nxp, shp;

    // phase 1: compute per-cell dots for view v into s_dot[v&1]
    auto phase1 = [&](int v) {
        const float* M = projp + (b * VS_ + v) * 12;
        float rx = M[0] * xf + M[1] * yf + M[2];
        float ry = M[3] * xf + M[4] * yf + M[5];
        float rz = M[6] * xf + M[7] * yf + M[8];

        float Zl = rz * d_lo + M[11]; if (Zl == 0.f) Zl = 1e-9f;
        float Zh = rz * d_hi + M[11]; if (Zh == 0.f) Zh = 1e-9f;
        float il = 1.f / Zl, ih = 1.f / Zh;
        float xl = (rx * d_lo + M[9]) * il, yl = (ry * d_lo + M[10]) * il;
        float xh = (rx * d_hi + M[9]) * ih, yh = (ry * d_hi + M[10]) * ih;

        float xmnf = fminf(fmaxf(fminf(xl, xh), -2.f), (float)(W_ + 1));
        float xmxf = fminf(fmaxf(fmaxf(xl, xh), -2.f), (float)(W_ + 1));
        float ymnf = fminf(fmaxf(fminf(yl, yh), -2.f), (float)(H_ + 1));
        float ymxf = fminf(fmaxf(fmaxf(yl, yh), -2.f), (float)(H_ + 1));

        xmn = max((int)floorf(xmnf), -1);
        ymn = max((int)floorf(ymnf), -1);
        int xmx = min(max((int)floorf(xmxf), xmn), min(W_ - 1, xmn + 14));
        int ymx = min(max((int)floorf(ymxf), ymn), min(H_ - 1, ymn + 6));
        nx = xmx - xmn + 2;                 // cells cover [xmn .. xmx+1]
        ny = ymx - ymn + 2;
        shp = (nx <= 4) ? 2 : ((nx <= 8) ? 3 : 4);
        nxp = 1 << shp;
        int ncp = nxp * ny;                 // <= 128

        const float4* sp = (const float4*)(srcT + (size_t)(v * B_ + b) * H_ * W_ * C_);
        float2* dot = &s_dot[v & 1][p][0];
        for (int ci = d; ci < ncp; ci += 32) {
            int cx = ci & (nxp - 1);
            if (cx < nx) {
                int cy = ci >> shp;
                int sx = min(max(xmn + cx, 0), W_ - 1);
                int sy = min(max(ymn + cy, 0), H_ - 1);
                const float4* cp = sp + ((size_t)sy * W_ + sx) * (C_ / 4);
                float dS = 0.f, dR = 0.f;
#pragma unroll
                for (int q = 0; q < 8; ++q) {
                    float4 sv = cp[q];
                    float4 r  = *(const float4*)&s_ref[p][q * 4];
                    float gq = r.x * sv.x + r.y * sv.y + r.z * sv.z + r.w * sv.w;
                    dS += gq;
                    dR += rwv[q] * gq;
                }
                dot[ci] = make_float2(dS, dR);
            }
        }
    };

    float cwsum = 1e-8f;
    float acc   = 0.f;

    phase1(0);
    // no barrier: s_dot flow is intra-wave (same half-wave writes and reads)

    for (int v = 0; v < VS_; ++v) {
        // save current view's bbox (phase1(v+1) overwrites the uniforms)
        int cxmn = xmn, cymn = ymn, cnx = nx, cny = ny, cnxp = nxp;

        if (v + 1 < VS_) phase1(v + 1);   // loads overlap phase-2 compute below

        // ---- phase 2: per-depth bilinear combine + view softmax ----
        const float* M = projp + (b * VS_ + v) * 12;
        float rx = M[0] * xf + M[1] * yf + M[2];
        float ry = M[3] * xf + M[4] * yf + M[5];
        float rz = M[6] * xf + M[7] * yf + M[8];
        float Z = rz * depth + M[11]; if (Z == 0.f) Z = 1e-9f;
        float iZ = 1.f / Z;
        float ix = (rx * depth + M[9]) * iZ;
        float iy = (ry * depth + M[10]) * iZ;
        float x0f = floorf(ix), y0f = floorf(iy);
        float wx1 = ix - x0f, wy1 = iy - y0f;
        float wx0 = 1.f - wx1, wy0 = 1.f - wy1;

        int x0 = (int)fminf(fmaxf(x0f, -2.f), (float)(W_ + 1));
        int y0 = (int)fminf(fmaxf(y0f, -2.f), (float)(H_ + 1));

        float vx0 = (x0f >= 0.f  && x0f <= (float)(W_ - 1)) ? 1.f : 0.f;
        float vx1 = (x0f >= -1.f && x0f <= (float)(W_ - 2)) ? 1.f : 0.f;
        float vy0 = (y0f >= 0.f  && y0f <= (float)(H_ - 1)) ? 1.f : 0.f;
        float vy1 = (y0f >= -1.f && y0f <= (float)(H_ - 2)) ? 1.f : 0.f;
        float ax0 = wx0 * vx0, ax1 = wx1 * vx1;
        float ay0 = wy0 * vy0, ay1 = wy1 * vy1;
        float w00 = ax0 * ay0, w10 = ax1 * ay0;
        float w01 = ax0 * ay1, w11 = ax1 * ay1;

        int cx0 = min(max(x0 - cxmn, 0), cnx - 2);
        int cy0 = min(max(y0 - cymn, 0), cny - 2);
        const float2* dot = &s_dot[v & 1][p][0];
        int cb = cy0 * cnxp + cx0;
        float2 d00 = dot[cb],        d10 = dot[cb + 1];
        float2 d01 = dot[cb + cnxp], d11 = dot[cb + cnxp + 1];
        float S = w00 * d00.x + w10 * d10.x + w01 * d01.x + w11 * d11.x;
        float R = w00 * d00.y + w10 * d10.y + w01 * d01.y + w11 * d11.y;

        // view softmax over D (32-lane butterfly)
        float t = S * 0.125f;   // *0.25 (group mean) * 0.5 (1/ATTN_TEMP)
        float m = t;
#pragma unroll
        for (int mask = 16; mask >= 1; mask >>= 1)
            m = fmaxf(m, __shfl_xor(m, mask));
        float e = __expf(t - m);
        float s = e;
#pragma unroll
        for (int mask = 16; mask >= 1; mask >>= 1)
            s += __shfl_xor(s, mask);
        float cw = e / s * 0.17677669529663689f;   // * 1/sqrt(C)
        cwsum += cw;
        acc   += cw * (R * 0.25f);
        // no barrier: buffer v&1 is re-written only by phase1(v+2), which is
        // later in this wave's program order than phase2(v)'s reads above
    }

    float logit = acc / cwsum;

    // final softmax over D
    float m = logit;
#pragma unroll
    for (int mask = 16; mask >= 1; mask >>= 1)
        m = fmaxf(m, __shfl_xor(m, mask));
    float e = __expf(logit - m);
    float s = e;
#pragma unroll
    for (int mask = 16; mask >= 1; mask >>= 1)
        s += __shfl_xor(s, mask);
    float attn = e / s;

    // argmax over D (first max wins, matching jnp.argmax)
    float bv = logit;
    int   bi = d;
#pragma unroll
    for (int mask = 16; mask >= 1; mask >>= 1) {
        float ov = __shfl_xor(bv, mask);
        int   oi = __shfl_xor(bi, mask);
        if (ov > bv || (ov == bv && oi < bi)) { bv = ov; bi = oi; }
    }

    if (d == 0) {
        out[((size_t)b * H_ + h) * W_ + w] = s_depth[p][bi];
    }

    // attn store via LDS transpose for 32B-segment coalescing (cross-wave)
    __shared__ float s_attn[8][33];
    s_attn[p][d] = attn;
    __syncthreads();   // cross-wave: barrier REQUIRED
    int po = tid & 7;
    int d2 = tid >> 3;
    float* attn_out = out + (size_t)B_ * H_ * W_;
    attn_out[(((size_t)b * D_ + d2) * H_ + h) * W_ + w0 + po] = s_attn[po][d2];
}

// ---------------------------------------------------------------------------
extern "C" void kernel_launch(void* const* d_in, const int* in_sizes, int n_in,
                              void* d_out, int out_size, void* d_ws, size_t ws_size,
                              hipStream_t stream) {
    const float* ref_fea    = (const float*)d_in[0];
    const float* src_feas   = (const float*)d_in[1];
    const float* proj       = (const float*)d_in[2];
    const float* depth_hypo = (const float*)d_in[3];
    const float* reg_w      = (const float*)d_in[4];
    float* out = (float*)d_out;

    float* projp = (float*)d_ws;                       // 72 floats used
    float* srcT  = projp + 256;                        // VS*B*H*W*C fp32

    setup_proj_kernel<<<1, 64, 0, stream>>>(proj, projp);
    transpose_kernel<<<VS_ * B_ * H_, 256, 0, stream>>>(src_feas, srcT);
    fused_kernel<<<B_ * H_ * (W_ / 8), 256, 0, stream>>>(ref_fea, srcT, projp,
                                                         depth_hypo, reg_w, out);
}